// Round 6
// baseline (40.396 us; speedup 1.0000x reference)
//
#include <hip/hip_runtime.h>

// LocallyConnected2d: out[b,o,l] = sum_d p[b,d,l]*w[d,l,o] + bias[o,l]
// B=8, DEPTH=288 (=32c x 3x3), L=2304, C_OUT=32, fp32. Weight = 85 MB read once.
// R6 = R5 traffic-pattern design with the cross-wave red race FIXED:
//   wave owns 4 l's x all 72 d; lane=(dpar,lsub,og); dpar reduced in-wave via
//   shfl_xor(16/32); red slots are per-(l,o) -> disjoint across waves.
//  - weight reads: per d-plane the block covers 16l x 32o = 2 KB contiguous
//  - x staged as contiguous rows into 20.7 KB slab (8b x 8c x 3kh x 18w)
//  - partials to d_ws as full 64 B lines; stage-2 reduces 4 dblks (+bias)

constexpr int NB=8, CIN=32, HWD=48, COUT=32, DEPTH=288, LTOT=2304;
constexpr int LB=16, NLT=LTOT/LB;     // 144 ltiles
constexpr int NDB=4, DCH=DEPTH/NDB;   // 4 d-blocks x 72 d (= 8 channels each)
constexpr int XS_PB=12;               // b-stride in xs (48 B, 16B-aligned)
constexpr int RPAD=36;                // red l-row stride (words)

__device__ __forceinline__ int XSI(int ci,int kh,int wi){ return ((ci*3+kh)*18+wi)*XS_PB; }

__global__ __launch_bounds__(256,4) void lc2d_s1(const float* __restrict__ x,
                                                 const float* __restrict__ wgt,
                                                 float* __restrict__ ws) {
    __shared__ float xs[8*3*18*XS_PB];   // 5184 floats = 20.7 KB
    __shared__ float red[NB*LB*RPAD];    // 4608 floats = 18.4 KB

    const int bid = blockIdx.x;
    const int xcd = bid & 7, r1 = bid >> 3;          // 576 % 8 == 0
    const int ltile = xcd*18 + (r1 % 18);            // ltile's XCD = ltile/18
    const int dblk  = r1 / 18;                       // 0..3
    const int l0 = ltile*LB;
    const int h0 = l0 / HWD, w0 = l0 - h0*HWD;       // 16 l's in one row
    const int c0 = dblk*8;
    const int tid = threadIdx.x;

    // ---- stage x slab: 8b x 8c x 3kh x 18w = 3456 elems, w-fastest ----
    #pragma unroll
    for (int k=0; k<14; ++k) {
        int idx = k*256 + tid;
        if (idx < 3456) {
            int wi = idx % 18; int t = idx / 18;
            int kh = t % 3;    t /= 3;
            int ci = t & 7;    int b = t >> 3;
            int ih = h0 + kh - 1, iw = w0 + wi - 1;
            float v = 0.f;
            if ((unsigned)ih < (unsigned)HWD && (unsigned)iw < (unsigned)HWD)
                v = x[((b*CIN + c0+ci)*HWD + ih)*HWD + iw];
            xs[XSI(ci,kh,wi) + b] = v;
        }
    }
    __syncthreads();

    // ---- main: wave owns l's [wave*4, wave*4+4); lane = (dpar, lsub, og) ----
    const int wave = tid >> 6, lane = tid & 63;
    const int og   = lane & 3;         // o = og*4..+3 (half0), 16+og*4..+3 (half1)
    const int lsub = (lane >> 2) & 3;
    const int dpar = lane >> 4;        // 0..3: d sub-range dpar*18 .. +18
    const int li   = wave*4 + lsub;    // 0..15 within ltile
    const size_t WSd = (size_t)LTOT * COUT;   // floats between d-planes

    const float* wb = wgt + ((size_t)(dblk*DCH + dpar*18)*LTOT + (size_t)(l0+li))*COUT + og*4;

    float4 acc[NB][2];
    #pragma unroll
    for (int b=0;b<NB;++b){ acc[b][0]=make_float4(0,0,0,0); acc[b][1]=make_float4(0,0,0,0); }

    float4 wa0 = *reinterpret_cast<const float4*>(wb);
    float4 wa1 = *reinterpret_cast<const float4*>(wb + 16);
    #pragma unroll
    for (int t=0; t<18; ++t) {
        float4 wn0, wn1;
        if (t < 17) {
            wn0 = *reinterpret_cast<const float4*>(wb + (size_t)(t+1)*WSd);
            wn1 = *reinterpret_cast<const float4*>(wb + (size_t)(t+1)*WSd + 16);
        }
        const int cl = dpar*2 + t/9;       // channel within slab (dpar*18 is 2 chans)
        const int kk = t % 9, kh = kk/3, kw = kk - kh*3;
        const float4 pA = *reinterpret_cast<const float4*>(&xs[XSI(cl,kh,li+kw)]);     // b0..3
        const float4 pB = *reinterpret_cast<const float4*>(&xs[XSI(cl,kh,li+kw) + 4]); // b4..7
        #define FM(bi, pv) \
            acc[bi][0].x = fmaf(pv, wa0.x, acc[bi][0].x); acc[bi][0].y = fmaf(pv, wa0.y, acc[bi][0].y); \
            acc[bi][0].z = fmaf(pv, wa0.z, acc[bi][0].z); acc[bi][0].w = fmaf(pv, wa0.w, acc[bi][0].w); \
            acc[bi][1].x = fmaf(pv, wa1.x, acc[bi][1].x); acc[bi][1].y = fmaf(pv, wa1.y, acc[bi][1].y); \
            acc[bi][1].z = fmaf(pv, wa1.z, acc[bi][1].z); acc[bi][1].w = fmaf(pv, wa1.w, acc[bi][1].w);
        FM(0, pA.x) FM(1, pA.y) FM(2, pA.z) FM(3, pA.w)
        FM(4, pB.x) FM(5, pB.y) FM(6, pB.z) FM(7, pB.w)
        #undef FM
        wa0 = wn0; wa1 = wn1;
    }

    // ---- reduce over dpar (lane bits 4,5): masks 16, 32 ----
    #pragma unroll
    for (int m = 16; m <= 32; m <<= 1) {
        #pragma unroll
        for (int b=0;b<NB;++b) {
            #pragma unroll
            for (int h=0;h<2;++h) {
                acc[b][h].x += __shfl_xor(acc[b][h].x, m);
                acc[b][h].y += __shfl_xor(acc[b][h].y, m);
                acc[b][h].z += __shfl_xor(acc[b][h].z, m);
                acc[b][h].w += __shfl_xor(acc[b][h].w, m);
            }
        }
    }

    // lanes dpar==0 hold complete dblk sums for (li, og); slots disjoint per wave
    if (dpar == 0) {
        #pragma unroll
        for (int b=0;b<NB;++b) {
            *reinterpret_cast<float4*>(&red[(b*LB+li)*RPAD + og*4])      = acc[b][0];
            *reinterpret_cast<float4*>(&red[(b*LB+li)*RPAD + og*4 + 16]) = acc[b][1];
        }
    }
    __syncthreads();

    // ---- thread = (b,o): gather 16 l, write one full 64 B line to ws ----
    const int ob = tid >> 5, oo = tid & 31;
    float v[LB];
    #pragma unroll
    for (int i=0;i<LB;++i) v[i] = red[(ob*LB+i)*RPAD + oo];
    float* dst = ws + (((size_t)(dblk*NB + ob)*COUT + oo)*LTOT + l0);
    #pragma unroll
    for (int q=0;q<4;++q)
        *reinterpret_cast<float4*>(dst + q*4) = make_float4(v[q*4], v[q*4+1], v[q*4+2], v[q*4+3]);
}

// stage 2: out[b,o,l] = sum_k ws[k][b][o][l] + bias[o][l]
__global__ __launch_bounds__(256, 8) void lc2d_s2(const float* __restrict__ ws,
                                                  const float* __restrict__ bias,
                                                  float* __restrict__ out) {
    const int bid = blockIdx.x;
    const int xcd = bid & 7, r2 = bid >> 3;
    const int ltile = xcd*18 + (r2 % 18);     // same XCD as this ltile's writers
    const int j = r2 / 18;                    // b-pair 2j, 2j+1
    const int l0 = ltile*LB;
    const int tid = threadIdx.x;
    const int lq = tid & 3;
    const int o  = (tid >> 2) & 31;
    const int b  = 2*j + (tid >> 7);
    const size_t loff = (size_t)l0 + lq*4;

    float4 s = *reinterpret_cast<const float4*>(bias + (size_t)o*LTOT + loff);
    #pragma unroll
    for (int k=0;k<NDB;++k) {
        const float4 p = *reinterpret_cast<const float4*>(ws + (((size_t)(k*NB+b)*COUT + o)*LTOT + loff));
        s.x += p.x; s.y += p.y; s.z += p.z; s.w += p.w;
    }
    *reinterpret_cast<float4*>(out + ((size_t)(b*COUT + o)*LTOT + loff)) = s;
}

extern "C" void kernel_launch(void* const* d_in, const int* in_sizes, int n_in,
                              void* d_out, int out_size, void* d_ws, size_t ws_size,
                              hipStream_t stream) {
    const float* x    = (const float*)d_in[0];
    const float* wgt  = (const float*)d_in[1];
    const float* bias = (const float*)d_in[2];
    float* out        = (float*)d_out;
    float* ws         = (float*)d_ws;   // needs 4*8*32*2304*4 = 9.44 MB
    lc2d_s1<<<NLT*NDB, 256, 0, stream>>>(x, wgt, ws);
    lc2d_s2<<<NLT*NDB, 256, 0, stream>>>(ws, bias, out);
}

// Round 7
// 31.606 us; speedup vs baseline: 1.2781x; 1.2781x over previous
//
#include <hip/hip_runtime.h>

// LocallyConnected2d: out[b,o,l] = sum_d p[b,d,l]*w[d,l,o] + bias[o,l]
// B=8, DEPTH=288 (=32c x 3x3), L=2304, C_OUT=32, fp32. Weight = 85 MB read once.
// R7 = R6 traffic design minus register spilling:
//   lane=(dpar2,bh2,lsub4,og4): acc = 4b x 8o = 32 VGPR; one shfl_xor(32) reduce.
//   red aliases xs (LDS 20.7 KB -> 7 blocks/CU); launch_bounds(256,2) = no cap.
//  - weight reads: per d-plane the block covers 16l x 32o = 2 KB contiguous
//  - partials to d_ws as full 64 B lines; stage-2 reduces 4 dblks (+bias)

constexpr int NB=8, CIN=32, HWD=48, COUT=32, DEPTH=288, LTOT=2304;
constexpr int LB=16, NLT=LTOT/LB;     // 144 ltiles
constexpr int NDB=4, DCH=DEPTH/NDB;   // 4 d-blocks x 72 d (= 8 channels each)
constexpr int XS_PB=12;               // b-stride in xs (48 B, 16B-aligned)
constexpr int RPAD=36;                // red l-row stride (words)

__device__ __forceinline__ int XSI(int ci,int kh,int wi){ return ((ci*3+kh)*18+wi)*XS_PB; }

__global__ __launch_bounds__(256,2) void lc2d_s1(const float* __restrict__ x,
                                                 const float* __restrict__ wgt,
                                                 float* __restrict__ ws) {
    __shared__ float lds[8*3*18*XS_PB];  // 5184 floats = 20.7 KB
    float* const xs  = lds;
    float* const red = lds;              // 4608 floats, reused AFTER barrier

    const int bid = blockIdx.x;
    const int xcd = bid & 7, r1 = bid >> 3;          // 576 % 8 == 0
    const int ltile = xcd*18 + (r1 % 18);            // ltile's XCD = ltile/18
    const int dblk  = r1 / 18;                       // 0..3
    const int l0 = ltile*LB;
    const int h0 = l0 / HWD, w0 = l0 - h0*HWD;       // 16 l's in one row
    const int c0 = dblk*8;
    const int tid = threadIdx.x;

    // ---- stage x slab: 8b x 8c x 3kh x 18w = 3456 elems, w-fastest ----
    #pragma unroll
    for (int k=0; k<14; ++k) {
        int idx = k*256 + tid;
        if (idx < 3456) {
            int wi = idx % 18; int t = idx / 18;
            int kh = t % 3;    t /= 3;
            int ci = t & 7;    int b = t >> 3;
            int ih = h0 + kh - 1, iw = w0 + wi - 1;
            float v = 0.f;
            if ((unsigned)ih < (unsigned)HWD && (unsigned)iw < (unsigned)HWD)
                v = x[((b*CIN + c0+ci)*HWD + ih)*HWD + iw];
            xs[XSI(ci,kh,wi) + b] = v;
        }
    }
    __syncthreads();

    // ---- main: wave owns l's [wave*4,+4); lane = (dpar, bh, lsub, og) ----
    const int wave = tid >> 6, lane = tid & 63;
    const int og   = lane & 3;         // o = og*4..+3 (half0), 16+og*4..+3 (half1)
    const int lsub = (lane >> 2) & 3;
    const int bh   = (lane >> 4) & 1;  // b-half: b = bh*4 .. bh*4+3
    const int dpar = lane >> 5;        // 0..1: d sub-range dpar*36 .. +36 (4 chans)
    const int li   = wave*4 + lsub;    // 0..15 within ltile
    const size_t WSd = (size_t)LTOT * COUT;   // floats between d-planes

    const float* wb = wgt + ((size_t)(dblk*DCH + dpar*36)*LTOT + (size_t)(l0+li))*COUT + og*4;
    const float* pb = xs + XSI(dpar*4, 0, li) + bh*4;   // this lane's b-half

    float4 acc[4][2];
    #pragma unroll
    for (int b=0;b<4;++b){ acc[b][0]=make_float4(0,0,0,0); acc[b][1]=make_float4(0,0,0,0); }

    float4 wa0 = *reinterpret_cast<const float4*>(wb);
    float4 wa1 = *reinterpret_cast<const float4*>(wb + 16);
    #pragma unroll
    for (int t=0; t<36; ++t) {
        float4 wn0, wn1;
        if (t < 35) {
            wn0 = *reinterpret_cast<const float4*>(wb + (size_t)(t+1)*WSd);
            wn1 = *reinterpret_cast<const float4*>(wb + (size_t)(t+1)*WSd + 16);
        }
        const int dc = t/9, kk = t%9, kh = kk/3, kw = kk - kh*3;
        const float4 p = *reinterpret_cast<const float4*>(pb + (dc*54 + kh*18 + kw)*XS_PB);
        #define FM(bi, pv) \
            acc[bi][0].x = fmaf(pv, wa0.x, acc[bi][0].x); acc[bi][0].y = fmaf(pv, wa0.y, acc[bi][0].y); \
            acc[bi][0].z = fmaf(pv, wa0.z, acc[bi][0].z); acc[bi][0].w = fmaf(pv, wa0.w, acc[bi][0].w); \
            acc[bi][1].x = fmaf(pv, wa1.x, acc[bi][1].x); acc[bi][1].y = fmaf(pv, wa1.y, acc[bi][1].y); \
            acc[bi][1].z = fmaf(pv, wa1.z, acc[bi][1].z); acc[bi][1].w = fmaf(pv, wa1.w, acc[bi][1].w);
        FM(0, p.x) FM(1, p.y) FM(2, p.z) FM(3, p.w)
        #undef FM
        wa0 = wn0; wa1 = wn1;
    }

    // ---- reduce over dpar (lane bit 5) ----
    #pragma unroll
    for (int b=0;b<4;++b) {
        #pragma unroll
        for (int h=0;h<2;++h) {
            acc[b][h].x += __shfl_xor(acc[b][h].x, 32);
            acc[b][h].y += __shfl_xor(acc[b][h].y, 32);
            acc[b][h].z += __shfl_xor(acc[b][h].z, 32);
            acc[b][h].w += __shfl_xor(acc[b][h].w, 32);
        }
    }

    __syncthreads();   // everyone done reading xs; safe to overwrite with red
    if (dpar == 0) {   // lanes 0..31 hold full dblk sums for (bh, li, og)
        #pragma unroll
        for (int b=0;b<4;++b) {
            const int bb = bh*4 + b;
            *reinterpret_cast<float4*>(&red[(bb*LB+li)*RPAD + og*4])      = acc[b][0];
            *reinterpret_cast<float4*>(&red[(bb*LB+li)*RPAD + og*4 + 16]) = acc[b][1];
        }
    }
    __syncthreads();

    // ---- thread = (b,o): gather 16 l, write one full 64 B line to ws ----
    const int ob = tid >> 5, oo = tid & 31;
    float v[LB];
    #pragma unroll
    for (int i=0;i<LB;++i) v[i] = red[(ob*LB+i)*RPAD + oo];
    float* dst = ws + (((size_t)(dblk*NB + ob)*COUT + oo)*LTOT + l0);
    #pragma unroll
    for (int q=0;q<4;++q)
        *reinterpret_cast<float4*>(dst + q*4) = make_float4(v[q*4], v[q*4+1], v[q*4+2], v[q*4+3]);
}

// stage 2: out[b,o,l] = sum_k ws[k][b][o][l] + bias[o][l]
__global__ __launch_bounds__(256, 8) void lc2d_s2(const float* __restrict__ ws,
                                                  const float* __restrict__ bias,
                                                  float* __restrict__ out) {
    const int bid = blockIdx.x;
    const int xcd = bid & 7, r2 = bid >> 3;
    const int ltile = xcd*18 + (r2 % 18);     // same XCD as this ltile's writers
    const int j = r2 / 18;                    // b-pair 2j, 2j+1
    const int l0 = ltile*LB;
    const int tid = threadIdx.x;
    const int lq = tid & 3;
    const int o  = (tid >> 2) & 31;
    const int b  = 2*j + (tid >> 7);
    const size_t loff = (size_t)l0 + lq*4;

    float4 s = *reinterpret_cast<const float4*>(bias + (size_t)o*LTOT + loff);
    #pragma unroll
    for (int k=0;k<NDB;++k) {
        const float4 p = *reinterpret_cast<const float4*>(ws + (((size_t)(k*NB+b)*COUT + o)*LTOT + loff));
        s.x += p.x; s.y += p.y; s.z += p.z; s.w += p.w;
    }
    *reinterpret_cast<float4*>(out + ((size_t)(b*COUT + o)*LTOT + loff)) = s;
}

extern "C" void kernel_launch(void* const* d_in, const int* in_sizes, int n_in,
                              void* d_out, int out_size, void* d_ws, size_t ws_size,
                              hipStream_t stream) {
    const float* x    = (const float*)d_in[0];
    const float* wgt  = (const float*)d_in[1];
    const float* bias = (const float*)d_in[2];
    float* out        = (float*)d_out;
    float* ws         = (float*)d_ws;   // needs 4*8*32*2304*4 = 9.44 MB
    lc2d_s1<<<NLT*NDB, 256, 0, stream>>>(x, wgt, ws);
    lc2d_s2<<<NLT*NDB, 256, 0, stream>>>(ws, bias, out);
}